// Round 5
// baseline (4527.398 us; speedup 1.0000x reference)
//
#include <hip/hip_runtime.h>

#define USER_NUM 200000
#define ITEM_NUM 100000
#define EMB 64

#define BROWS 256                                   // rows per bucket
#define NB ((USER_NUM + BROWS - 1) / BROWS)         // 782 buckets
#define PTILE 8192                                  // edges per partition tile
#define PTHREADS 512
#define COLMASK 0x3FFFFu                            // 18 bits, cols < 262144

// ---------------------------------------------------------------------------
// Step A: per-bucket edge histogram (782 bins, LDS-staged, tiny global traffic)
// ---------------------------------------------------------------------------
__global__ __launch_bounds__(256) void bucket_hist_kernel(
    const int* __restrict__ rows, int nnz, int* __restrict__ gcnt)
{
    __shared__ int h[NB];
    for (int i = threadIdx.x; i < NB; i += 256) h[i] = 0;
    __syncthreads();
    int stride = gridDim.x * 256;
    for (int e = blockIdx.x * 256 + threadIdx.x; e < nnz; e += stride)
        atomicAdd(&h[rows[e] >> 8], 1);
    __syncthreads();
    for (int i = threadIdx.x; i < NB; i += 256) {
        int v = h[i];
        if (v) atomicAdd(&gcnt[i], v);
    }
}

// ---------------------------------------------------------------------------
// Step B: exclusive scan of 782 bucket counts (one 1024-thread block).
// Writes gbase[0..NB] and initializes gcursor = gbase.
// ---------------------------------------------------------------------------
__global__ __launch_bounds__(1024) void scan_buckets_kernel(
    const int* __restrict__ gcnt, int* __restrict__ gbase,
    int* __restrict__ gcursor)
{
    __shared__ int sm[1024];
    int tid = threadIdx.x;
    int v = (tid < NB) ? gcnt[tid] : 0;
    sm[tid] = v; __syncthreads();
    for (int off = 1; off < 1024; off <<= 1) {
        int a = (tid >= off) ? sm[tid - off] : 0;
        __syncthreads();
        sm[tid] += a;
        __syncthreads();
    }
    if (tid < NB) {
        int excl = sm[tid] - v;
        gbase[tid] = excl;
        gcursor[tid] = excl;
        if (tid == NB - 1) gbase[NB] = sm[tid];
    }
}

// ---------------------------------------------------------------------------
// Step C: partition edges into bucket-contiguous order.
// Per 8192-edge tile: LDS hist -> block scan -> reserve global ranges ->
// LDS reorder -> COALESCED chunked flush (avg 16 edges = 128B contiguous per
// bucket per tile, vs 8B random stores in the old scatter: ~4x less line amp).
// Payload: (rlocal<<18 | col, val) packed in 8B.
// Dynamic LDS: stage[PTILE] uint2 (64KB) + sb[PTILE] u16 (16KB).
// ---------------------------------------------------------------------------
__global__ __launch_bounds__(PTHREADS) void partition_kernel(
    const int* __restrict__ rows, const int* __restrict__ cols,
    const float* __restrict__ vals, int nnz,
    int* __restrict__ gcursor, uint2* __restrict__ epart)
{
    __shared__ int hist[NB];     // counts -> exclusive local offsets
    __shared__ int cur[NB];
    __shared__ int gbaseb[NB];
    __shared__ int psum[PTHREADS];
    extern __shared__ char dyn[];
    uint2* stage = (uint2*)dyn;                              // 64 KB
    unsigned short* sb = (unsigned short*)(dyn + PTILE * 8); // 16 KB

    int tid = threadIdx.x;
    int base = blockIdx.x * PTILE;
    int cnt = nnz - base; if (cnt > PTILE) cnt = PTILE;

    for (int i = tid; i < NB; i += PTHREADS) { hist[i] = 0; cur[i] = 0; }
    __syncthreads();

    // 1. local histogram (coalesced row reads)
    for (int k = tid; k < cnt; k += PTHREADS)
        atomicAdd(&hist[rows[base + k] >> 8], 1);
    __syncthreads();

    // 2. block scan of hist (2 bins/thread covers 1024 >= NB)
    int b0 = tid * 2, b1 = tid * 2 + 1;
    int h0 = (b0 < NB) ? hist[b0] : 0;
    int h1 = (b1 < NB) ? hist[b1] : 0;
    int s = h0 + h1;
    psum[tid] = s; __syncthreads();
    for (int off = 1; off < PTHREADS; off <<= 1) {
        int a = (tid >= off) ? psum[tid - off] : 0;
        __syncthreads();
        psum[tid] += a;
        __syncthreads();
    }
    int run = psum[tid] - s;                 // exclusive prefix
    if (b0 < NB) hist[b0] = run;             // overwrite with local offsets
    if (b1 < NB) hist[b1] = run + h0;
    // 3. reserve global space per bucket
    if (b0 < NB && h0 > 0) gbaseb[b0] = atomicAdd(&gcursor[b0], h0);
    if (b1 < NB && h1 > 0) gbaseb[b1] = atomicAdd(&gcursor[b1], h1);
    __syncthreads();

    // 4. reorder into LDS staging (bucket-sorted within tile)
    for (int k = tid; k < cnt; k += PTHREADS) {
        int e = base + k;
        int r = rows[e];
        int b = r >> 8;
        unsigned int packed = ((unsigned)(r & 255) << 18) | (unsigned)cols[e];
        int pos = hist[b] + atomicAdd(&cur[b], 1);
        stage[pos] = make_uint2(packed, __float_as_uint(vals[e]));
        sb[pos] = (unsigned short)b;
    }
    __syncthreads();

    // 5. coalesced flush: consecutive slots -> consecutive global addresses
    for (int j = tid; j < cnt; j += PTHREADS) {
        int b = sb[j];
        epart[gbaseb[b] + (j - hist[b])] = stage[j];
    }
}

// ---------------------------------------------------------------------------
// Bucket SpMM: out[row] = (addin ? addin[row] : 0) + sum val*X[col]
// One WG per bucket; acc[256][64] f32 in 64KB LDS (2 WG/CU).
// Wave-per-edge, lane=dim: 256B coalesced gather + ds_add_f32 (2-way free).
// Unroll-4 -> 32 outstanding gathers/CU to cover L3 latency.
// No row_ptr, no per-row sort needed.
// ---------------------------------------------------------------------------
__global__ __launch_bounds__(256, 2) void spmm_bucket_kernel(
    const int* __restrict__ gbase, const uint2* __restrict__ epart,
    const float* __restrict__ X, const float* __restrict__ addin,
    float* __restrict__ out, int n_rows)
{
    __shared__ float acc[BROWS * EMB];   // 64 KB
    int tid = threadIdx.x;
    int b = blockIdx.x;
    int row0 = b << 8;

    #pragma unroll
    for (int i = 0; i < 16; ++i)
        reinterpret_cast<float4*>(acc)[tid + i * 256] = make_float4(0, 0, 0, 0);
    __syncthreads();

    int beg = gbase[b], end = gbase[b + 1];
    int wid = tid >> 6, lane = tid & 63;

    int i = beg + wid;
    for (; i + 12 < end; i += 16) {
        uint2 e0 = epart[i];
        uint2 e1 = epart[i + 4];
        uint2 e2 = epart[i + 8];
        uint2 e3 = epart[i + 12];
        float x0 = X[(size_t)(e0.x & COLMASK) * EMB + lane];
        float x1 = X[(size_t)(e1.x & COLMASK) * EMB + lane];
        float x2 = X[(size_t)(e2.x & COLMASK) * EMB + lane];
        float x3 = X[(size_t)(e3.x & COLMASK) * EMB + lane];
        atomicAdd(&acc[(e0.x >> 18) * EMB + lane], __uint_as_float(e0.y) * x0);
        atomicAdd(&acc[(e1.x >> 18) * EMB + lane], __uint_as_float(e1.y) * x1);
        atomicAdd(&acc[(e2.x >> 18) * EMB + lane], __uint_as_float(e2.y) * x2);
        atomicAdd(&acc[(e3.x >> 18) * EMB + lane], __uint_as_float(e3.y) * x3);
    }
    for (; i < end; i += 4) {
        uint2 e0 = epart[i];
        float x0 = X[(size_t)(e0.x & COLMASK) * EMB + lane];
        atomicAdd(&acc[(e0.x >> 18) * EMB + lane], __uint_as_float(e0.y) * x0);
    }
    __syncthreads();

    int nr = n_rows - row0; if (nr > BROWS) nr = BROWS;
    int totalf4 = nr * (EMB / 4);
    for (int f = tid; f < totalf4; f += 256) {
        float4 v = reinterpret_cast<const float4*>(acc)[f];
        size_t g = (size_t)row0 * (EMB / 4) + f;
        if (addin) {
            float4 a = reinterpret_cast<const float4*>(addin)[g];
            v.x += a.x; v.y += a.y; v.z += a.z; v.w += a.w;
        }
        reinterpret_cast<float4*>(out)[g] = v;
    }
}

// ---------------------------------------------------------------------------
// Fallback SpMM (atomic path) — used only if ws_size too small.
// ---------------------------------------------------------------------------
__global__ __launch_bounds__(256) void spmm_atomic_kernel(
    const int* __restrict__ rows, const int* __restrict__ cols,
    const float* __restrict__ vals, const float* __restrict__ X,
    float* __restrict__ out, int nnz)
{
    int t = blockIdx.x * 256 + threadIdx.x;
    int e = t >> 4;
    if (e >= nnz) return;
    int q = (t & 15) << 2;
    int r = rows[e];
    int c = cols[e];
    float v = vals[e];
    float4 x = *reinterpret_cast<const float4*>(X + (size_t)c * EMB + q);
    float* o = out + (size_t)r * EMB + q;
    atomicAdd(o + 0, v * x.x);
    atomicAdd(o + 1, v * x.y);
    atomicAdd(o + 2, v * x.z);
    atomicAdd(o + 3, v * x.w);
}

// ---------------------------------------------------------------------------
// Dense layer (round-4 version: spill-free, LDS-staged W, 2 users/thread).
// ---------------------------------------------------------------------------
#define DENSE_BLOCKS 512
#define DENSE_SPAN (DENSE_BLOCKS * 256)   // 131072

__global__ __launch_bounds__(256, 2) void dense_relu_kernel(
    const float* __restrict__ agg, const float* __restrict__ Uin,
    const float* __restrict__ W,     // [64][128] row-major (out,in)
    const float* __restrict__ bias,  // [64]
    float* __restrict__ Uout, int nrows)
{
    __shared__ float Wl[64 * 128 + 64];
    int tid = threadIdx.x;
    #pragma unroll
    for (int i = 0; i < 8; ++i) {
        int idx = tid + i * 256;
        reinterpret_cast<float4*>(Wl)[idx] = reinterpret_cast<const float4*>(W)[idx];
    }
    if (tid < 64) Wl[8192 + tid] = bias[tid];
    __syncthreads();

    int gid = blockIdx.x * 256 + tid;
    int u0 = gid;
    int u1 = gid + DENSE_SPAN;
    bool ok1 = (u1 < nrows);
    if (u0 >= nrows) return;

    float acc[2][EMB];
    #pragma unroll
    for (int k = 0; k < EMB; ++k) {
        float bv = Wl[8192 + k];
        acc[0][k] = bv;
        acc[1][k] = bv;
    }

    #pragma unroll 1
    for (int half = 0; half < 2; ++half) {
        const float* __restrict__ src = half ? Uin : agg;
        const float4* r0 = reinterpret_cast<const float4*>(src + (size_t)u0 * EMB);
        const float4* r1 = ok1 ? reinterpret_cast<const float4*>(src + (size_t)u1 * EMB)
                               : r0;
        #pragma unroll 1
        for (int jq = 0; jq < 16; ++jq) {
            float4 h0 = r0[jq];
            float4 h1 = r1[jq];
            #pragma unroll
            for (int k = 0; k < EMB; ++k) {
                float4 wv = *reinterpret_cast<const float4*>(
                    Wl + k * 128 + half * 64 + jq * 4);
                acc[0][k] = fmaf(h0.x, wv.x, acc[0][k]);
                acc[0][k] = fmaf(h0.y, wv.y, acc[0][k]);
                acc[0][k] = fmaf(h0.z, wv.z, acc[0][k]);
                acc[0][k] = fmaf(h0.w, wv.w, acc[0][k]);
                acc[1][k] = fmaf(h1.x, wv.x, acc[1][k]);
                acc[1][k] = fmaf(h1.y, wv.y, acc[1][k]);
                acc[1][k] = fmaf(h1.z, wv.z, acc[1][k]);
                acc[1][k] = fmaf(h1.w, wv.w, acc[1][k]);
            }
        }
    }

    {
        float* orow = Uout + (size_t)u0 * EMB;
        #pragma unroll
        for (int q = 0; q < 16; ++q) {
            float4 o;
            o.x = fmaxf(acc[0][q*4+0], 0.f);
            o.y = fmaxf(acc[0][q*4+1], 0.f);
            o.z = fmaxf(acc[0][q*4+2], 0.f);
            o.w = fmaxf(acc[0][q*4+3], 0.f);
            reinterpret_cast<float4*>(orow)[q] = o;
        }
    }
    if (ok1) {
        float* orow = Uout + (size_t)u1 * EMB;
        #pragma unroll
        for (int q = 0; q < 16; ++q) {
            float4 o;
            o.x = fmaxf(acc[1][q*4+0], 0.f);
            o.y = fmaxf(acc[1][q*4+1], 0.f);
            o.z = fmaxf(acc[1][q*4+2], 0.f);
            o.w = fmaxf(acc[1][q*4+3], 0.f);
            reinterpret_cast<float4*>(orow)[q] = o;
        }
    }
}

// ---------------------------------------------------------------------------
static void build_buckets(const int* rows, const int* cols, const float* vals,
                          int nnz, int* gcnt, int* gbase, int* gcursor,
                          uint2* epart, hipStream_t stream)
{
    hipMemsetAsync(gcnt, 0, NB * sizeof(int), stream);
    bucket_hist_kernel<<<1024, 256, 0, stream>>>(rows, nnz, gcnt);
    scan_buckets_kernel<<<1, 1024, 0, stream>>>(gcnt, gbase, gcursor);
    int ptiles = (nnz + PTILE - 1) / PTILE;
    partition_kernel<<<ptiles, PTHREADS, PTILE * 10, stream>>>(
        rows, cols, vals, nnz, gcursor, epart);
}

extern "C" void kernel_launch(void* const* d_in, const int* in_sizes, int n_in,
                              void* d_out, int out_size, void* d_ws, size_t ws_size,
                              hipStream_t stream) {
    const float* user_emb = (const float*)d_in[0];   // [200000,64]
    const float* item_emb = (const float*)d_in[1];   // [100000,64]
    const float* W        = (const float*)d_in[2];   // [2,64,128]
    const float* b        = (const float*)d_in[3];   // [2,64]
    const int*   s_rows   = (const int*)d_in[4];
    const int*   s_cols   = (const int*)d_in[5];
    const float* s_vals   = (const float*)d_in[6];
    const int*   r_rows   = (const int*)d_in[7];
    const int*   r_cols   = (const int*)d_in[8];
    const float* r_vals   = (const float*)d_in[9];

    int ne_s = in_sizes[4];
    int ne_r = in_sizes[7];

    float* out      = (float*)d_out;
    float* user_out = out;                                  // [200000,64]
    float* item_out = out + (size_t)USER_NUM * EMB;         // [100000,64]

    // ---- workspace layout ----
    char* w = (char*)d_ws;
    float* agg      = (float*)w;  w += (size_t)USER_NUM * EMB * 4;
    uint2* s_part   = (uint2*)w;  w += (size_t)ne_s * 8;
    uint2* r_part   = (uint2*)w;  w += (size_t)ne_r * 8;
    int*   gcnt     = (int*)w;    w += (size_t)NB * 4;
    int*   gbase_s  = (int*)w;    w += (size_t)(NB + 1) * 4;
    int*   gbase_r  = (int*)w;    w += (size_t)(NB + 1) * 4;
    int*   gcursor  = (int*)w;    w += (size_t)NB * 4;
    size_t needed = (size_t)(w - (char*)d_ws);

    size_t aggBytes = (size_t)USER_NUM * EMB * sizeof(float);

    if (ws_size >= needed) {
        // ---- bucket path: no random global scatter, no f32 global atomics ----
        build_buckets(s_rows, s_cols, s_vals, ne_s, gcnt, gbase_s, gcursor,
                      s_part, stream);
        build_buckets(r_rows, r_cols, r_vals, ne_r, gcnt, gbase_r, gcursor,
                      r_part, stream);

        // Layer 0
        spmm_bucket_kernel<<<NB, 256, 0, stream>>>(
            gbase_s, s_part, user_emb, nullptr, agg, USER_NUM);
        dense_relu_kernel<<<DENSE_BLOCKS, 256, 0, stream>>>(
            agg, user_emb, W, b, user_out, USER_NUM);

        // Layer 1 (in-place on user_out)
        spmm_bucket_kernel<<<NB, 256, 0, stream>>>(
            gbase_s, s_part, user_out, nullptr, agg, USER_NUM);
        dense_relu_kernel<<<DENSE_BLOCKS, 256, 0, stream>>>(
            agg, user_out, W + 64 * 128, b + 64, user_out, USER_NUM);

        // user_all = U2 + R @ item_emb
        spmm_bucket_kernel<<<NB, 256, 0, stream>>>(
            gbase_r, r_part, item_emb, user_out, user_out, USER_NUM);
    } else {
        // ---- fallback: atomic path (needs only agg) ----
        int spmmBlocksS = (ne_s * 16 + 255) / 256;
        int spmmBlocksR = (ne_r * 16 + 255) / 256;
        hipMemsetAsync(agg, 0, aggBytes, stream);
        spmm_atomic_kernel<<<spmmBlocksS, 256, 0, stream>>>(s_rows, s_cols, s_vals,
                                                            user_emb, agg, ne_s);
        dense_relu_kernel<<<DENSE_BLOCKS, 256, 0, stream>>>(agg, user_emb, W, b,
                                                            user_out, USER_NUM);
        hipMemsetAsync(agg, 0, aggBytes, stream);
        spmm_atomic_kernel<<<spmmBlocksS, 256, 0, stream>>>(s_rows, s_cols, s_vals,
                                                            user_out, agg, ne_s);
        dense_relu_kernel<<<DENSE_BLOCKS, 256, 0, stream>>>(agg, user_out,
                                                            W + 64 * 128, b + 64,
                                                            user_out, USER_NUM);
        spmm_atomic_kernel<<<spmmBlocksR, 256, 0, stream>>>(r_rows, r_cols, r_vals,
                                                            item_emb, user_out, ne_r);
    }

    // item_all = item_emb (passthrough)
    hipMemcpyAsync(item_out, item_emb, (size_t)ITEM_NUM * EMB * sizeof(float),
                   hipMemcpyDeviceToDevice, stream);
}